// Round 17
// baseline (98.347 us; speedup 1.0000x reference)
//
#include <hip/hip_runtime.h>
#include <hip/hip_bf16.h>
#include <stdint.h>

#define NTOK 8192
#define DIM  512
#define QKVW 1536

typedef __attribute__((ext_vector_type(8))) short bf16x8;
typedef __attribute__((ext_vector_type(4))) float f32x4;

static __device__ __forceinline__ unsigned short f2b(float f) {
    union { float f; unsigned int u; } v; v.f = f;
    unsigned int r = v.u + 0x7fffu + ((v.u >> 16) & 1u);
    return (unsigned short)(r >> 16);
}

static __device__ __forceinline__ float b2f(unsigned short u) {
    union { unsigned int i; float f; } v; v.i = ((unsigned int)u) << 16;
    return v.f;
}

static __device__ __forceinline__ void gld_lds16(const void* g, void* l) {
    __builtin_amdgcn_global_load_lds(
        (__attribute__((address_space(1))) void*)(uintptr_t)g,
        (__attribute__((address_space(3))) void*)(uintptr_t)l,
        16, 0, 0);
}

#define SBAR() do { __builtin_amdgcn_sched_barrier(0); __builtin_amdgcn_s_barrier(); __builtin_amdgcn_sched_barrier(0); } while (0)
#define VMW0() do { __builtin_amdgcn_sched_barrier(0); asm volatile("s_waitcnt vmcnt(0)" ::: "memory"); __builtin_amdgcn_sched_barrier(0); } while (0)

// ---------------- converts ----------------

__global__ void f2b_kernel(const float* __restrict__ src, unsigned short* __restrict__ dst, int n4) {
    int i = blockIdx.x * blockDim.x + threadIdx.x;
    if (i < n4) {
        float4 f = ((const float4*)src)[i];
        ushort4 o;
        o.x = f2b(f.x); o.y = f2b(f.y); o.z = f2b(f.z); o.w = f2b(f.w);
        ((ushort4*)dst)[i] = o;
    }
}

__global__ void bias_concat(const float* __restrict__ bq, const float* __restrict__ bk,
                            const float* __restrict__ bv, float* __restrict__ bc) {
    int i = blockIdx.x * blockDim.x + threadIdx.x;
    if (i < 512)       bc[i] = bq[i];
    else if (i < 1024) bc[i] = bk[i - 512];
    else if (i < 1536) bc[i] = bv[i - 1024];
}

// ---------------- K|V transpose:  KVt[c][j] = QKV[j][512+c],  c in [0,1024) ----------------
__global__ void transpose_kv(const unsigned short* __restrict__ qkv, unsigned short* __restrict__ kvt) {
    __shared__ unsigned short t[64][65];
    int j0 = blockIdx.x * 64;
    int c0 = blockIdx.y * 64;
    int tid = threadIdx.x;
    int c  = tid & 63;
    int r4 = tid >> 6;
    #pragma unroll
    for (int r = r4; r < 64; r += 4)
        t[r][c] = qkv[(size_t)(j0 + r) * QKVW + 512 + c0 + c];
    __syncthreads();
    #pragma unroll
    for (int r = r4; r < 64; r += 4)
        kvt[(size_t)(c0 + r) * NTOK + j0 + c] = t[c][r];
}

// ---------------- 2-phase 128x256 bf16 GEMM, C = A * B^T (r9/r14/r16-verified) ----------------
// Coalesced XOR-involution staging (0-conflict), double buffer, setprio.
// EPI 0: bf16 store + bias[col]                      (QKV)
// EPI 2: fp32 split-K partial store                  (GHt partials)
// EPI 4: fused TU epilogue: bn<2 -> rowdot(T,Q) atomicAdd into nrm (T never
//        stored); bn>=2 -> fp32 U store at col-512.  (TU)
template <int EPI, int CH, int NT>
__global__ __launch_bounds__(256, 2) void gemmx(
    const unsigned short* __restrict__ A, int lda,
    const unsigned short* __restrict__ B, int ldb,
    void* __restrict__ Cout, int ldc,
    const float* __restrict__ bias,
    const unsigned short* __restrict__ Qb,
    float* __restrict__ nrm) {

    __shared__ __align__(16) char lds[49152];

    const int t = threadIdx.x;
    const int l = t & 63, w = t >> 6;
    const int wr = w >> 1, wc = w & 1;

    int bm, bn;
    if constexpr (CH == 0) {
        bm = blockIdx.y; bn = blockIdx.x;
    } else {
        const int gx = gridDim.x;
        const int nbm = gridDim.y >> 3;
        const int bid = blockIdx.y * gx + blockIdx.x;
        const int xcd = bid & 7, qq = bid >> 3;
        const int win = nbm * CH;
        const int grp = qq / win, rr = qq % win;
        bm = xcd * nbm + rr / CH;
        bn = grp * CH + rr % CH;
    }

    const int kt0 = blockIdx.z * (NT * 32);   // elements

    const unsigned short* srcA0;
    const unsigned short* srcA1;
    const unsigned short* srcB0;
    const unsigned short* srcB1;
    const unsigned short* srcB2;
    const unsigned short* srcB3;
    {
        int c, row, p;
        c = t;         row = c >> 2; p = (c & 3) ^ ((c >> 3) & 3);
        srcA0 = A + (size_t)(bm * 128 + row) * lda + kt0 + p * 8;
        c = 256 + t;   row = c >> 2; p = (c & 3) ^ ((c >> 3) & 3);
        srcA1 = A + (size_t)(bm * 128 + row) * lda + kt0 + p * 8;
        c = t;         row = c >> 2; p = (c & 3) ^ ((c >> 3) & 3);
        srcB0 = B + (size_t)(bn * 256 + row) * ldb + kt0 + p * 8;
        c = 256 + t;   row = c >> 2; p = (c & 3) ^ ((c >> 3) & 3);
        srcB1 = B + (size_t)(bn * 256 + row) * ldb + kt0 + p * 8;
        c = 512 + t;   row = c >> 2; p = (c & 3) ^ ((c >> 3) & 3);
        srcB2 = B + (size_t)(bn * 256 + row) * ldb + kt0 + p * 8;
        c = 768 + t;   row = c >> 2; p = (c & 3) ^ ((c >> 3) & 3);
        srcB3 = B + (size_t)(bn * 256 + row) * ldb + kt0 + p * 8;
    }

    auto STAGE = [&](int buf, int tt) {
        char* d = lds + buf * 24576 + w * 1024;
        const int o = tt * 32;
        gld_lds16(srcA0 + o, d);
        gld_lds16(srcA1 + o, d + 4096);
        gld_lds16(srcB0 + o, d + 8192);
        gld_lds16(srcB1 + o, d + 12288);
        gld_lds16(srcB2 + o, d + 16384);
        gld_lds16(srcB3 + o, d + 20480);
    };

    f32x4 acc[4][8] = {};

    const int lr = l & 15, Q = l >> 4;
    const int sw = ((Q ^ ((lr >> 1) & 3)) << 4);
    const int lrA = (wr * 64 + lr) * 64 + sw;
    const int lrB = 8192 + (wc * 128 + lr) * 64 + sw;

    STAGE(0, 0);
    VMW0();
    SBAR();

    #pragma unroll
    for (int tt = 0; tt < NT; ++tt) {
        const int cur = tt & 1;
        const bool more = (tt + 1 < NT);
        if (more) STAGE(cur ^ 1, tt + 1);
        __builtin_amdgcn_sched_barrier(0);

        const char* lb = lds + cur * 24576;
        bf16x8 af[4], bf[8];
        #pragma unroll
        for (int m = 0; m < 4; ++m) af[m] = *(const bf16x8*)(lb + lrA + m * 1024);
        #pragma unroll
        for (int n = 0; n < 8; ++n) bf[n] = *(const bf16x8*)(lb + lrB + n * 1024);

        __builtin_amdgcn_s_setprio(1);
        #pragma unroll
        for (int m = 0; m < 4; ++m)
            #pragma unroll
            for (int n = 0; n < 8; ++n)
                acc[m][n] = __builtin_amdgcn_mfma_f32_16x16x32_bf16(af[m], bf[n], acc[m][n], 0, 0, 0);
        __builtin_amdgcn_s_setprio(0);

        if (more) {
            VMW0();
            SBAR();
        }
    }

    const int rbase = bm * 128 + wr * 64;
    const int cbase = bn * 256 + wc * 128;
    const int g4 = Q * 4;

    if constexpr (EPI == 0) {
        unsigned short* C = (unsigned short*)Cout;
        #pragma unroll
        for (int m = 0; m < 4; ++m)
            #pragma unroll
            for (int n = 0; n < 8; ++n)
                #pragma unroll
                for (int j = 0; j < 4; ++j) {
                    int rrow = rbase + m * 16 + g4 + j;
                    int ccol = cbase + n * 16 + lr;
                    C[(size_t)rrow * ldc + ccol] = f2b(acc[m][n][j] + bias[ccol]);
                }
    } else if constexpr (EPI == 2) {
        float* C = (float*)Cout + (size_t)blockIdx.z * (gridDim.y * 128) * ldc;
        #pragma unroll
        for (int m = 0; m < 4; ++m)
            #pragma unroll
            for (int n = 0; n < 8; ++n)
                #pragma unroll
                for (int j = 0; j < 4; ++j) {
                    int rrow = rbase + m * 16 + g4 + j;
                    int ccol = cbase + n * 16 + lr;
                    C[(size_t)rrow * ldc + ccol] = acc[m][n][j];
                }
    } else {
        if (bn < 2) {
            // T-part: rowdot(T, Q) partial -> nrm (T never stored)
            #pragma unroll
            for (int m = 0; m < 4; ++m)
                #pragma unroll
                for (int j = 0; j < 4; ++j) {
                    int rrow = rbase + m * 16 + g4 + j;
                    float p = 0.f;
                    #pragma unroll
                    for (int n = 0; n < 8; ++n) {
                        float qv = b2f(Qb[(size_t)rrow * QKVW + cbase + n * 16 + lr]);
                        p += acc[m][n][j] * qv;
                    }
                    p += __shfl_xor(p, 1);
                    p += __shfl_xor(p, 2);
                    p += __shfl_xor(p, 4);
                    p += __shfl_xor(p, 8);
                    if (lr == 0) atomicAdd(&nrm[rrow], p);
                }
        } else {
            // U-part: fp32 store at col-512
            float* C = (float*)Cout;
            #pragma unroll
            for (int m = 0; m < 4; ++m)
                #pragma unroll
                for (int n = 0; n < 8; ++n)
                    #pragma unroll
                    for (int j = 0; j < 4; ++j) {
                        int rrow = rbase + m * 16 + g4 + j;
                        int ccol = cbase - 512 + n * 16 + lr;
                        C[(size_t)rrow * ldc + ccol] = acc[m][n][j];
                    }
        }
    }
}

// ---------------- GHt split-K reduce + bf16 cast (coalesced, no transpose) ----------------
// part: [16][1024*512] fp32 ;  ght[i] = bf16( sum_z part[z][i] )
__global__ void reduce_gh(const float* __restrict__ part, unsigned short* __restrict__ ght) {
    int i = blockIdx.x * 256 + threadIdx.x;   // over 1024*512/4 = 131072
    float4 s = ((const float4*)part)[i];
    #pragma unroll
    for (int z = 1; z < 16; ++z) {
        float4 v = ((const float4*)part)[i + (size_t)z * 131072];
        s.x += v.x; s.y += v.y; s.z += v.z; s.w += v.w;
    }
    ushort4 o;
    o.x = f2b(s.x); o.y = f2b(s.y); o.z = f2b(s.z); o.w = f2b(s.w);
    ((ushort4*)ght)[i] = o;
}

// ---------------- final: out = U * rsqrt(max(sqrt(nrm), eps)) ----------------
__global__ void final_norm(const float* __restrict__ U, const float* __restrict__ nrm,
                           float* __restrict__ out) {
    int i = blockIdx.x * 256 + threadIdx.x;   // over 8192*512/4 = 1048576
    float4 u = ((const float4*)U)[i];
    int row = i >> 7;
    float inv = 1.0f / fmaxf(sqrtf(nrm[row]), 1e-12f);
    float4 o;
    o.x = u.x * inv; o.y = u.y * inv; o.z = u.z * inv; o.w = u.w * inv;
    ((float4*)out)[i] = o;
}

extern "C" void kernel_launch(void* const* d_in, const int* in_sizes, int n_in,
                              void* d_out, int out_size, void* d_ws, size_t ws_size,
                              hipStream_t stream) {
    const float* x  = (const float*)d_in[0];
    const float* Wq = (const float*)d_in[1];
    const float* bq = (const float*)d_in[2];
    const float* Wk = (const float*)d_in[3];
    const float* bk = (const float*)d_in[4];
    const float* Wv = (const float*)d_in[5];
    const float* bv = (const float*)d_in[6];
    float* out = (float*)d_out;

    char* ws = (char*)d_ws;
    size_t off = 0;
    auto alloc = [&](size_t bytes) -> void* {
        void* p = ws + off;
        off = (off + bytes + 255) & ~(size_t)255;
        return p;
    };

    unsigned short* xb   = (unsigned short*)alloc((size_t)NTOK * DIM * 2);
    unsigned short* Wb   = (unsigned short*)alloc((size_t)QKVW * DIM * 2);
    float*          bc   = (float*)alloc(QKVW * 4);
    unsigned short* QKVb = (unsigned short*)alloc((size_t)NTOK * QKVW * 2);
    unsigned short* KVt  = (unsigned short*)alloc((size_t)1024 * NTOK * 2);
    float*          GHp  = (float*)alloc((size_t)16 * 1024 * 512 * 4);
    unsigned short* GHt  = (unsigned short*)alloc((size_t)1024 * 512 * 2);
    float*          Ubuf = (float*)alloc((size_t)NTOK * DIM * 4);
    float*          nrm  = (float*)alloc(NTOK * 4);

    // converts + zero nrm
    f2b_kernel<<<(NTOK * DIM / 4 + 255) / 256, 256, 0, stream>>>(x, xb, NTOK * DIM / 4);
    f2b_kernel<<<(DIM * DIM / 4 + 255) / 256, 256, 0, stream>>>(Wq, Wb, DIM * DIM / 4);
    f2b_kernel<<<(DIM * DIM / 4 + 255) / 256, 256, 0, stream>>>(Wk, Wb + DIM * DIM, DIM * DIM / 4);
    f2b_kernel<<<(DIM * DIM / 4 + 255) / 256, 256, 0, stream>>>(Wv, Wb + 2 * DIM * DIM, DIM * DIM / 4);
    bias_concat<<<6, 256, 0, stream>>>(bq, bk, bv, bc);
    hipMemsetAsync(nrm, 0, NTOK * 4, stream);

    // QKV(bf16) = x @ Wb^T + bias   [8192 x 1536], K=512
    gemmx<0, 6, 16><<<dim3(QKVW / 256, NTOK / 128), 256, 0, stream>>>(
        xb, DIM, Wb, DIM, QKVb, QKVW, bc, nullptr, nullptr);

    // KVt[c][j] = QKV[j][512+c]   [1024 x 8192]
    transpose_kv<<<dim3(NTOK / 64, 1024 / 64), 256, 0, stream>>>(QKVb, KVt);

    // GHt partials: GHt = KVt @ Kt^T   [1024 x 512], K=8192 split 16
    gemmx<2, 2, 16><<<dim3(512 / 256, 1024 / 128, 16), 256, 0, stream>>>(
        KVt, NTOK, KVt, NTOK, GHp, 512, nullptr, nullptr, nullptr);

    // GHt(bf16)[c][d] = sum_z GHp[z][c][d]   [1024 x 512]
    reduce_gh<<<1024 * 512 / 4 / 256, 256, 0, stream>>>(GHp, GHt);

    // TU = Q @ GHt^T: T-cols fused into nrm rowdot; U stored fp32 [8192 x 512]
    gemmx<4, 4, 16><<<dim3(1024 / 256, NTOK / 128), 256, 0, stream>>>(
        QKVb, QKVW, GHt, 512, Ubuf, DIM, nullptr, QKVb, nrm);

    // out = U * rsqrt(max(sqrt(nrm), eps))
    final_norm<<<NTOK * DIM / 4 / 256, 256, 0, stream>>>(Ubuf, nrm, out);
}

// Round 18
// 91.556 us; speedup vs baseline: 1.0742x; 1.0742x over previous
//
#include <hip/hip_runtime.h>
#include <hip/hip_bf16.h>
#include <stdint.h>

#define NTOK 8192
#define DIM  512
#define QKVW 1536

typedef __attribute__((ext_vector_type(8))) short bf16x8;
typedef __attribute__((ext_vector_type(4))) float f32x4;

static __device__ __forceinline__ unsigned short f2b(float f) {
    union { float f; unsigned int u; } v; v.f = f;
    unsigned int r = v.u + 0x7fffu + ((v.u >> 16) & 1u);
    return (unsigned short)(r >> 16);
}

static __device__ __forceinline__ float b2f(unsigned short u) {
    union { unsigned int i; float f; } v; v.i = ((unsigned int)u) << 16;
    return v.f;
}

static __device__ __forceinline__ void gld_lds16(const void* g, void* l) {
    __builtin_amdgcn_global_load_lds(
        (__attribute__((address_space(1))) void*)(uintptr_t)g,
        (__attribute__((address_space(3))) void*)(uintptr_t)l,
        16, 0, 0);
}

#define SBAR() do { __builtin_amdgcn_sched_barrier(0); __builtin_amdgcn_s_barrier(); __builtin_amdgcn_sched_barrier(0); } while (0)
#define VMW0() do { __builtin_amdgcn_sched_barrier(0); asm volatile("s_waitcnt vmcnt(0)" ::: "memory"); __builtin_amdgcn_sched_barrier(0); } while (0)

// ---------------- converts ----------------

__global__ void f2b_kernel(const float* __restrict__ src, unsigned short* __restrict__ dst, int n4) {
    int i = blockIdx.x * blockDim.x + threadIdx.x;
    if (i < n4) {
        float4 f = ((const float4*)src)[i];
        ushort4 o;
        o.x = f2b(f.x); o.y = f2b(f.y); o.z = f2b(f.z); o.w = f2b(f.w);
        ((ushort4*)dst)[i] = o;
    }
}

__global__ void bias_concat(const float* __restrict__ bq, const float* __restrict__ bk,
                            const float* __restrict__ bv, float* __restrict__ bc) {
    int i = blockIdx.x * blockDim.x + threadIdx.x;
    if (i < 512)       bc[i] = bq[i];
    else if (i < 1024) bc[i] = bk[i - 512];
    else if (i < 1536) bc[i] = bv[i - 1024];
}

// ---------------- K|V transpose:  KVt[c][j] = QKV[j][512+c],  c in [0,1024) ----------------
__global__ void transpose_kv(const unsigned short* __restrict__ qkv, unsigned short* __restrict__ kvt) {
    __shared__ unsigned short t[64][65];
    int j0 = blockIdx.x * 64;
    int c0 = blockIdx.y * 64;
    int tid = threadIdx.x;
    int c  = tid & 63;
    int r4 = tid >> 6;
    #pragma unroll
    for (int r = r4; r < 64; r += 4)
        t[r][c] = qkv[(size_t)(j0 + r) * QKVW + 512 + c0 + c];
    __syncthreads();
    #pragma unroll
    for (int r = r4; r < 64; r += 4)
        kvt[(size_t)(c0 + r) * NTOK + j0 + c] = t[c][r];
}

// ---------------- 2-phase 128x256 bf16 GEMM, C = A*B^T + bias (QKV only) ----------------
template <int CH, int NT>
__global__ __launch_bounds__(256, 2) void gemmx(
    const unsigned short* __restrict__ A, int lda,
    const unsigned short* __restrict__ B, int ldb,
    unsigned short* __restrict__ Cout, int ldc,
    const float* __restrict__ bias) {

    __shared__ __align__(16) char lds[49152];

    const int t = threadIdx.x;
    const int l = t & 63, w = t >> 6;
    const int wr = w >> 1, wc = w & 1;

    const int gx = gridDim.x;
    const int nbm = gridDim.y >> 3;
    const int bid = blockIdx.y * gx + blockIdx.x;
    const int xcd = bid & 7, qq = bid >> 3;
    const int win = nbm * CH;
    const int grp = qq / win, rr = qq % win;
    const int bm = xcd * nbm + rr / CH;
    const int bn = grp * CH + rr % CH;

    const unsigned short* srcA0;
    const unsigned short* srcA1;
    const unsigned short* srcB0;
    const unsigned short* srcB1;
    const unsigned short* srcB2;
    const unsigned short* srcB3;
    {
        int c, row, p;
        c = t;         row = c >> 2; p = (c & 3) ^ ((c >> 3) & 3);
        srcA0 = A + (size_t)(bm * 128 + row) * lda + p * 8;
        c = 256 + t;   row = c >> 2; p = (c & 3) ^ ((c >> 3) & 3);
        srcA1 = A + (size_t)(bm * 128 + row) * lda + p * 8;
        c = t;         row = c >> 2; p = (c & 3) ^ ((c >> 3) & 3);
        srcB0 = B + (size_t)(bn * 256 + row) * ldb + p * 8;
        c = 256 + t;   row = c >> 2; p = (c & 3) ^ ((c >> 3) & 3);
        srcB1 = B + (size_t)(bn * 256 + row) * ldb + p * 8;
        c = 512 + t;   row = c >> 2; p = (c & 3) ^ ((c >> 3) & 3);
        srcB2 = B + (size_t)(bn * 256 + row) * ldb + p * 8;
        c = 768 + t;   row = c >> 2; p = (c & 3) ^ ((c >> 3) & 3);
        srcB3 = B + (size_t)(bn * 256 + row) * ldb + p * 8;
    }

    auto STAGE = [&](int buf, int tt) {
        char* d = lds + buf * 24576 + w * 1024;
        const int o = tt * 32;
        gld_lds16(srcA0 + o, d);
        gld_lds16(srcA1 + o, d + 4096);
        gld_lds16(srcB0 + o, d + 8192);
        gld_lds16(srcB1 + o, d + 12288);
        gld_lds16(srcB2 + o, d + 16384);
        gld_lds16(srcB3 + o, d + 20480);
    };

    f32x4 acc[4][8] = {};

    const int lr = l & 15, Q = l >> 4;
    const int sw = ((Q ^ ((lr >> 1) & 3)) << 4);
    const int lrA = (wr * 64 + lr) * 64 + sw;
    const int lrB = 8192 + (wc * 128 + lr) * 64 + sw;

    STAGE(0, 0);
    VMW0();
    SBAR();

    #pragma unroll
    for (int tt = 0; tt < NT; ++tt) {
        const int cur = tt & 1;
        const bool more = (tt + 1 < NT);
        if (more) STAGE(cur ^ 1, tt + 1);
        __builtin_amdgcn_sched_barrier(0);

        const char* lb = lds + cur * 24576;
        bf16x8 af[4], bf[8];
        #pragma unroll
        for (int m = 0; m < 4; ++m) af[m] = *(const bf16x8*)(lb + lrA + m * 1024);
        #pragma unroll
        for (int n = 0; n < 8; ++n) bf[n] = *(const bf16x8*)(lb + lrB + n * 1024);

        __builtin_amdgcn_s_setprio(1);
        #pragma unroll
        for (int m = 0; m < 4; ++m)
            #pragma unroll
            for (int n = 0; n < 8; ++n)
                acc[m][n] = __builtin_amdgcn_mfma_f32_16x16x32_bf16(af[m], bf[n], acc[m][n], 0, 0, 0);
        __builtin_amdgcn_s_setprio(0);

        if (more) {
            VMW0();
            SBAR();
        }
    }

    const int rbase = bm * 128 + wr * 64;
    const int cbase = bn * 256 + wc * 128;
    const int g4 = Q * 4;

    #pragma unroll
    for (int m = 0; m < 4; ++m)
        #pragma unroll
        for (int n = 0; n < 8; ++n)
            #pragma unroll
            for (int j = 0; j < 4; ++j) {
                int rrow = rbase + m * 16 + g4 + j;
                int ccol = cbase + n * 16 + lr;
                Cout[(size_t)rrow * ldc + ccol] = f2b(acc[m][n][j] + bias[ccol]);
            }
}

// ---------------- 2-phase 128x128 bf16 GEMM (r7-verified core), 4 blocks/CU ----------------
// EPI 2: bf16 partial store at z-offset (GH)
// EPI 4: fused TU: bn<4 -> rowdot(T,Q) atomicAdd nrm; bn>=4 -> fp32 U store
template <int EPI, int CH, int NT>
__global__ __launch_bounds__(256, 4) void gemm7(
    const unsigned short* __restrict__ A, int lda,
    const unsigned short* __restrict__ B, int ldb,
    void* __restrict__ Cout, int ldc,
    const unsigned short* __restrict__ Qb,
    float* __restrict__ nrm) {

    __shared__ __align__(16) char lds[32768];

    const int t = threadIdx.x;
    const int l = t & 63, w = t >> 6;
    const int wr = w >> 1, wc = w & 1;

    int bm, bn;
    if constexpr (CH == 0) {
        bm = blockIdx.y; bn = blockIdx.x;
    } else {
        const int gx = gridDim.x;
        const int nbm = gridDim.y >> 3;
        const int bid = blockIdx.y * gx + blockIdx.x;
        const int xcd = bid & 7, qq = bid >> 3;
        const int win = nbm * CH;
        const int grp = qq / win, rr = qq % win;
        bm = xcd * nbm + rr / CH;
        bn = grp * CH + rr % CH;
    }

    const int kt0 = blockIdx.z * (NT * 32);   // elements

    const int c0 = w * 128 + l;
    const int c1 = c0 + 64;
    const int r0 = c0 >> 2, r1 = c1 >> 2;
    const int col0 = (((c0 & 3) ^ ((c0 >> 3) & 3)) << 3);
    const int col1 = (((c1 & 3) ^ ((c1 >> 3) & 3)) << 3);
    const unsigned short* gA0 = A + (size_t)(bm * 128 + r0) * lda + kt0 + col0;
    const unsigned short* gA1 = A + (size_t)(bm * 128 + r1) * lda + kt0 + col1;
    const unsigned short* gB0 = B + (size_t)(bn * 128 + r0) * ldb + kt0 + col0;
    const unsigned short* gB1 = B + (size_t)(bn * 128 + r1) * ldb + kt0 + col1;

    auto STAGE = [&](int buf, int tt) {
        char* d = lds + buf * 16384 + w * 2048;
        const int o = tt * 32;
        gld_lds16(gA0 + o, d);
        gld_lds16(gA1 + o, d + 1024);
        gld_lds16(gB0 + o, d + 8192);
        gld_lds16(gB1 + o, d + 8192 + 1024);
    };

    f32x4 acc[4][4] = {};

    const int lr = l & 15, Q = l >> 4;
    const int sw = ((Q ^ ((lr >> 1) & 3)) << 4);
    const int lrA = (wr * 64 + lr) * 64 + sw;
    const int lrB = 8192 + (wc * 64 + lr) * 64 + sw;

    STAGE(0, 0);
    VMW0();
    SBAR();

    #pragma unroll
    for (int tt = 0; tt < NT; ++tt) {
        const int cur = tt & 1;
        const bool more = (tt + 1 < NT);
        if (more) STAGE(cur ^ 1, tt + 1);
        __builtin_amdgcn_sched_barrier(0);

        const char* lb = lds + cur * 16384;
        bf16x8 af[4], bf[4];
        #pragma unroll
        for (int m = 0; m < 4; ++m) af[m] = *(const bf16x8*)(lb + lrA + m * 1024);
        #pragma unroll
        for (int n = 0; n < 4; ++n) bf[n] = *(const bf16x8*)(lb + lrB + n * 1024);

        __builtin_amdgcn_s_setprio(1);
        #pragma unroll
        for (int m = 0; m < 4; ++m)
            #pragma unroll
            for (int n = 0; n < 4; ++n)
                acc[m][n] = __builtin_amdgcn_mfma_f32_16x16x32_bf16(af[m], bf[n], acc[m][n], 0, 0, 0);
        __builtin_amdgcn_s_setprio(0);

        if (more) {
            VMW0();
            SBAR();
        }
    }

    const int rbase = bm * 128 + wr * 64;
    const int cbase = bn * 128 + wc * 64;
    const int g4 = Q * 4;

    if constexpr (EPI == 2) {
        // bf16 partial store at z-offset
        unsigned short* C = (unsigned short*)Cout + (size_t)blockIdx.z * 524288;
        #pragma unroll
        for (int m = 0; m < 4; ++m)
            #pragma unroll
            for (int n = 0; n < 4; ++n)
                #pragma unroll
                for (int j = 0; j < 4; ++j) {
                    int rrow = rbase + m * 16 + g4 + j;
                    int ccol = cbase + n * 16 + lr;
                    C[(size_t)rrow * ldc + ccol] = f2b(acc[m][n][j]);
                }
    } else {
        if (bn < 4) {
            // T-part: rowdot(T, Q) partial -> nrm (T never stored)
            #pragma unroll
            for (int m = 0; m < 4; ++m)
                #pragma unroll
                for (int j = 0; j < 4; ++j) {
                    int rrow = rbase + m * 16 + g4 + j;
                    float p = 0.f;
                    #pragma unroll
                    for (int n = 0; n < 4; ++n) {
                        float qv = b2f(Qb[(size_t)rrow * QKVW + cbase + n * 16 + lr]);
                        p += acc[m][n][j] * qv;
                    }
                    p += __shfl_xor(p, 1);
                    p += __shfl_xor(p, 2);
                    p += __shfl_xor(p, 4);
                    p += __shfl_xor(p, 8);
                    if (lr == 0) atomicAdd(&nrm[rrow], p);
                }
        } else {
            // U-part: fp32 store at col-512
            float* C = (float*)Cout;
            #pragma unroll
            for (int m = 0; m < 4; ++m)
                #pragma unroll
                for (int n = 0; n < 4; ++n)
                    #pragma unroll
                    for (int j = 0; j < 4; ++j) {
                        int rrow = rbase + m * 16 + g4 + j;
                        int ccol = cbase - 512 + n * 16 + lr;
                        C[(size_t)rrow * ldc + ccol] = acc[m][n][j];
                    }
        }
    }
}

// ---------------- GHt split-K reduce (bf16 partials) + bf16 cast ----------------
__global__ void reduce_gh(const unsigned short* __restrict__ part, unsigned short* __restrict__ ght) {
    int i = blockIdx.x * 256 + threadIdx.x;   // over 524288/4 = 131072 ushort4
    float4 s = {0.f, 0.f, 0.f, 0.f};
    #pragma unroll
    for (int z = 0; z < 16; ++z) {
        ushort4 v = ((const ushort4*)(part + (size_t)z * 524288))[i];
        s.x += b2f(v.x); s.y += b2f(v.y); s.z += b2f(v.z); s.w += b2f(v.w);
    }
    ushort4 o;
    o.x = f2b(s.x); o.y = f2b(s.y); o.z = f2b(s.z); o.w = f2b(s.w);
    ((ushort4*)ght)[i] = o;
}

// ---------------- final: out = U * rsqrt(max(sqrt(nrm), eps)) ----------------
__global__ void final_norm(const float* __restrict__ U, const float* __restrict__ nrm,
                           float* __restrict__ out) {
    int i = blockIdx.x * 256 + threadIdx.x;
    float4 u = ((const float4*)U)[i];
    int row = i >> 7;
    float inv = 1.0f / fmaxf(sqrtf(nrm[row]), 1e-12f);
    float4 o;
    o.x = u.x * inv; o.y = u.y * inv; o.z = u.z * inv; o.w = u.w * inv;
    ((float4*)out)[i] = o;
}

extern "C" void kernel_launch(void* const* d_in, const int* in_sizes, int n_in,
                              void* d_out, int out_size, void* d_ws, size_t ws_size,
                              hipStream_t stream) {
    const float* x  = (const float*)d_in[0];
    const float* Wq = (const float*)d_in[1];
    const float* bq = (const float*)d_in[2];
    const float* Wk = (const float*)d_in[3];
    const float* bk = (const float*)d_in[4];
    const float* Wv = (const float*)d_in[5];
    const float* bv = (const float*)d_in[6];
    float* out = (float*)d_out;

    char* ws = (char*)d_ws;
    size_t off = 0;
    auto alloc = [&](size_t bytes) -> void* {
        void* p = ws + off;
        off = (off + bytes + 255) & ~(size_t)255;
        return p;
    };

    unsigned short* xb   = (unsigned short*)alloc((size_t)NTOK * DIM * 2);
    unsigned short* Wb   = (unsigned short*)alloc((size_t)QKVW * DIM * 2);
    float*          bc   = (float*)alloc(QKVW * 4);
    unsigned short* QKVb = (unsigned short*)alloc((size_t)NTOK * QKVW * 2);
    unsigned short* KVt  = (unsigned short*)alloc((size_t)1024 * NTOK * 2);
    unsigned short* GHp  = (unsigned short*)alloc((size_t)16 * 1024 * 512 * 2);
    unsigned short* GHt  = (unsigned short*)alloc((size_t)1024 * 512 * 2);
    float*          Ubuf = (float*)alloc((size_t)NTOK * DIM * 4);
    float*          nrm  = (float*)alloc(NTOK * 4);

    // converts + zero nrm
    f2b_kernel<<<(NTOK * DIM / 4 + 255) / 256, 256, 0, stream>>>(x, xb, NTOK * DIM / 4);
    f2b_kernel<<<(DIM * DIM / 4 + 255) / 256, 256, 0, stream>>>(Wq, Wb, DIM * DIM / 4);
    f2b_kernel<<<(DIM * DIM / 4 + 255) / 256, 256, 0, stream>>>(Wk, Wb + DIM * DIM, DIM * DIM / 4);
    f2b_kernel<<<(DIM * DIM / 4 + 255) / 256, 256, 0, stream>>>(Wv, Wb + 2 * DIM * DIM, DIM * DIM / 4);
    bias_concat<<<6, 256, 0, stream>>>(bq, bk, bv, bc);
    hipMemsetAsync(nrm, 0, NTOK * 4, stream);

    // QKV(bf16) = x @ Wb^T + bias   [8192 x 1536], K=512
    gemmx<6, 16><<<dim3(QKVW / 256, NTOK / 128), 256, 0, stream>>>(
        xb, DIM, Wb, DIM, QKVb, QKVW, bc);

    // KVt[c][j] = QKV[j][512+c]   [1024 x 8192]
    transpose_kv<<<dim3(NTOK / 64, 1024 / 64), 256, 0, stream>>>(QKVb, KVt);

    // GHt partials (bf16): GHt = KVt @ Kt^T   [1024 x 512], K=8192 split 16
    // grid (4, 8, 16) = 512 blocks -> 2 blocks/CU
    gemm7<2, 0, 16><<<dim3(512 / 128, 1024 / 128, 16), 256, 0, stream>>>(
        KVt, NTOK, KVt, NTOK, GHp, 512, nullptr, nullptr);

    // GHt(bf16) = sum_z GHp[z]   [1024 x 512]
    reduce_gh<<<512, 256, 0, stream>>>(GHp, GHt);

    // TU = Q @ GHt^T: T-cols (bn<4) fused into nrm rowdot; U stored fp32
    // grid (8, 64) = 512 blocks -> 2 blocks/CU
    gemm7<4, 8, 16><<<dim3(1024 / 128, NTOK / 128), 256, 0, stream>>>(
        QKVb, QKVW, GHt, 512, Ubuf, DIM, QKVb, nrm);

    // out = U * rsqrt(max(sqrt(nrm), eps))
    final_norm<<<NTOK * DIM / 4 / 256, 256, 0, stream>>>(Ubuf, nrm, out);
}

// Round 19
// 83.090 us; speedup vs baseline: 1.1836x; 1.1019x over previous
//
#include <hip/hip_runtime.h>
#include <hip/hip_bf16.h>
#include <stdint.h>

#define NTOK 8192
#define DIM  512
#define QKVW 1536

typedef __attribute__((ext_vector_type(8))) short bf16x8;
typedef __attribute__((ext_vector_type(4))) float f32x4;

static __device__ __forceinline__ unsigned short f2b(float f) {
    union { float f; unsigned int u; } v; v.f = f;
    unsigned int r = v.u + 0x7fffu + ((v.u >> 16) & 1u);
    return (unsigned short)(r >> 16);
}

static __device__ __forceinline__ float b2f(unsigned short u) {
    union { unsigned int i; float f; } v; v.i = ((unsigned int)u) << 16;
    return v.f;
}

static __device__ __forceinline__ void gld_lds16(const void* g, void* l) {
    __builtin_amdgcn_global_load_lds(
        (__attribute__((address_space(1))) void*)(uintptr_t)g,
        (__attribute__((address_space(3))) void*)(uintptr_t)l,
        16, 0, 0);
}

#define SBAR() do { __builtin_amdgcn_sched_barrier(0); __builtin_amdgcn_s_barrier(); __builtin_amdgcn_sched_barrier(0); } while (0)
#define VMW0() do { __builtin_amdgcn_sched_barrier(0); asm volatile("s_waitcnt vmcnt(0)" ::: "memory"); __builtin_amdgcn_sched_barrier(0); } while (0)
#define LGKM0() do { __builtin_amdgcn_sched_barrier(0); asm volatile("s_waitcnt lgkmcnt(0)" ::: "memory"); __builtin_amdgcn_sched_barrier(0); } while (0)

// ---------------- converts ----------------

__global__ void f2b_kernel(const float* __restrict__ src, unsigned short* __restrict__ dst, int n4) {
    int i = blockIdx.x * blockDim.x + threadIdx.x;
    if (i < n4) {
        float4 f = ((const float4*)src)[i];
        ushort4 o;
        o.x = f2b(f.x); o.y = f2b(f.y); o.z = f2b(f.z); o.w = f2b(f.w);
        ((ushort4*)dst)[i] = o;
    }
}

__global__ void bias_concat(const float* __restrict__ bq, const float* __restrict__ bk,
                            const float* __restrict__ bv, float* __restrict__ bc) {
    int i = blockIdx.x * blockDim.x + threadIdx.x;
    if (i < 512)       bc[i] = bq[i];
    else if (i < 1024) bc[i] = bk[i - 512];
    else if (i < 1536) bc[i] = bv[i - 1024];
}

// ------- QKV GEMM 128x256: Q rows -> Qb[8192x512]; K/V -> KVt[1024x8192] transposed -------
// Core loop = r9/r14-verified 2-phase. Epilogue for bn>=2 does a per-wave LDS
// transpose: col-major [64c][72r-pad] tile, ds_write_b64 of each lane's 4-row
// acc quad, then coalesced 8B/lane global stores of KVt rows.
template <int CH, int NT>
__global__ __launch_bounds__(256, 2) void gemm_qkv(
    const unsigned short* __restrict__ A, int lda,
    const unsigned short* __restrict__ B, int ldb,
    unsigned short* __restrict__ Qb,
    unsigned short* __restrict__ KVt,
    const float* __restrict__ bias) {

    __shared__ __align__(16) char lds[49152];

    const int t = threadIdx.x;
    const int l = t & 63, w = t >> 6;
    const int wr = w >> 1, wc = w & 1;

    const int gx = gridDim.x;
    const int nbm = gridDim.y >> 3;
    const int bid = blockIdx.y * gx + blockIdx.x;
    const int xcd = bid & 7, qq = bid >> 3;
    const int win = nbm * CH;
    const int grp = qq / win, rr = qq % win;
    const int bm = xcd * nbm + rr / CH;
    const int bn = grp * CH + rr % CH;

    const unsigned short* srcA0;
    const unsigned short* srcA1;
    const unsigned short* srcB0;
    const unsigned short* srcB1;
    const unsigned short* srcB2;
    const unsigned short* srcB3;
    {
        int c, row, p;
        c = t;         row = c >> 2; p = (c & 3) ^ ((c >> 3) & 3);
        srcA0 = A + (size_t)(bm * 128 + row) * lda + p * 8;
        c = 256 + t;   row = c >> 2; p = (c & 3) ^ ((c >> 3) & 3);
        srcA1 = A + (size_t)(bm * 128 + row) * lda + p * 8;
        c = t;         row = c >> 2; p = (c & 3) ^ ((c >> 3) & 3);
        srcB0 = B + (size_t)(bn * 256 + row) * ldb + p * 8;
        c = 256 + t;   row = c >> 2; p = (c & 3) ^ ((c >> 3) & 3);
        srcB1 = B + (size_t)(bn * 256 + row) * ldb + p * 8;
        c = 512 + t;   row = c >> 2; p = (c & 3) ^ ((c >> 3) & 3);
        srcB2 = B + (size_t)(bn * 256 + row) * ldb + p * 8;
        c = 768 + t;   row = c >> 2; p = (c & 3) ^ ((c >> 3) & 3);
        srcB3 = B + (size_t)(bn * 256 + row) * ldb + p * 8;
    }

    auto STAGE = [&](int buf, int tt) {
        char* d = lds + buf * 24576 + w * 1024;
        const int o = tt * 32;
        gld_lds16(srcA0 + o, d);
        gld_lds16(srcA1 + o, d + 4096);
        gld_lds16(srcB0 + o, d + 8192);
        gld_lds16(srcB1 + o, d + 12288);
        gld_lds16(srcB2 + o, d + 16384);
        gld_lds16(srcB3 + o, d + 20480);
    };

    f32x4 acc[4][8] = {};

    const int lr = l & 15, Q = l >> 4;
    const int sw = ((Q ^ ((lr >> 1) & 3)) << 4);
    const int lrA = (wr * 64 + lr) * 64 + sw;
    const int lrB = 8192 + (wc * 128 + lr) * 64 + sw;

    STAGE(0, 0);
    VMW0();
    SBAR();

    #pragma unroll
    for (int tt = 0; tt < NT; ++tt) {
        const int cur = tt & 1;
        const bool more = (tt + 1 < NT);
        if (more) STAGE(cur ^ 1, tt + 1);
        __builtin_amdgcn_sched_barrier(0);

        const char* lb = lds + cur * 24576;
        bf16x8 af[4], bf[8];
        #pragma unroll
        for (int m = 0; m < 4; ++m) af[m] = *(const bf16x8*)(lb + lrA + m * 1024);
        #pragma unroll
        for (int n = 0; n < 8; ++n) bf[n] = *(const bf16x8*)(lb + lrB + n * 1024);

        __builtin_amdgcn_s_setprio(1);
        #pragma unroll
        for (int m = 0; m < 4; ++m)
            #pragma unroll
            for (int n = 0; n < 8; ++n)
                acc[m][n] = __builtin_amdgcn_mfma_f32_16x16x32_bf16(af[m], bf[n], acc[m][n], 0, 0, 0);
        __builtin_amdgcn_s_setprio(0);

        if (more) {
            VMW0();
            SBAR();
        }
    }

    const int rbase = bm * 128 + wr * 64;
    const int cbase = bn * 256 + wc * 128;
    const int g4 = Q * 4;

    if (bn < 2) {
        // Q region: row-major store into Qb (ldc = 512)
        #pragma unroll
        for (int m = 0; m < 4; ++m)
            #pragma unroll
            for (int n = 0; n < 8; ++n)
                #pragma unroll
                for (int j = 0; j < 4; ++j) {
                    int rrow = rbase + m * 16 + g4 + j;
                    int ccol = cbase + n * 16 + lr;
                    Qb[(size_t)rrow * 512 + ccol] = f2b(acc[m][n][j] + bias[ccol]);
                }
    } else {
        // K/V region: per-wave LDS transpose -> KVt[c][j] stores
        SBAR();   // all waves done with staging buffers
        unsigned short* wt = (unsigned short*)(lds + w * 12288);   // [64c][72r]
        #pragma unroll
        for (int h = 0; h < 2; ++h) {
            // write phase: lane's 4-row quad (cols cloc = nn*16+lr)
            #pragma unroll
            for (int m = 0; m < 4; ++m)
                #pragma unroll
                for (int nn = 0; nn < 4; ++nn) {
                    int n = h * 4 + nn;
                    int cloc = nn * 16 + lr;
                    int ccol = cbase + n * 16 + lr;
                    uint2 v;
                    unsigned short s0 = f2b(acc[m][n][0] + bias[ccol]);
                    unsigned short s1 = f2b(acc[m][n][1] + bias[ccol]);
                    unsigned short s2 = f2b(acc[m][n][2] + bias[ccol]);
                    unsigned short s3 = f2b(acc[m][n][3] + bias[ccol]);
                    v.x = (unsigned int)s0 | ((unsigned int)s1 << 16);
                    v.y = (unsigned int)s2 | ((unsigned int)s3 << 16);
                    *(uint2*)(wt + cloc * 72 + m * 16 + g4) = v;
                }
            LGKM0();
            // read + coalesced global store: c = cc*4 + Q, r = lr*4..lr*4+3
            const int kvb = cbase + h * 64 - 512;
            #pragma unroll
            for (int cc = 0; cc < 16; ++cc) {
                int c = cc * 4 + Q;
                uint2 v = *(const uint2*)(wt + c * 72 + lr * 4);
                *(uint2*)&KVt[(size_t)(kvb + c) * NTOK + rbase + lr * 4] = v;
            }
            if (h == 0) LGKM0();
        }
    }
}

// ---------------- 2-phase 128x128 bf16 GEMM (r7-verified core), 4 blocks/CU ----------------
// EPI 2: bf16 partial store at z-offset (GH)
// EPI 4: fused TU: bn<4 -> rowdot(T,Q) atomicAdd nrm; bn>=4 -> bf16 U store
template <int EPI, int CH, int NT>
__global__ __launch_bounds__(256, 4) void gemm7(
    const unsigned short* __restrict__ A, int lda,
    const unsigned short* __restrict__ B, int ldb,
    void* __restrict__ Cout, int ldc,
    const unsigned short* __restrict__ Qb,
    float* __restrict__ nrm) {

    __shared__ __align__(16) char lds[32768];

    const int t = threadIdx.x;
    const int l = t & 63, w = t >> 6;
    const int wr = w >> 1, wc = w & 1;

    int bm, bn;
    if constexpr (CH == 0) {
        bm = blockIdx.y; bn = blockIdx.x;
    } else {
        const int gx = gridDim.x;
        const int nbm = gridDim.y >> 3;
        const int bid = blockIdx.y * gx + blockIdx.x;
        const int xcd = bid & 7, qq = bid >> 3;
        const int win = nbm * CH;
        const int grp = qq / win, rr = qq % win;
        bm = xcd * nbm + rr / CH;
        bn = grp * CH + rr % CH;
    }

    const int kt0 = blockIdx.z * (NT * 32);

    const int c0 = w * 128 + l;
    const int c1 = c0 + 64;
    const int r0 = c0 >> 2, r1 = c1 >> 2;
    const int col0 = (((c0 & 3) ^ ((c0 >> 3) & 3)) << 3);
    const int col1 = (((c1 & 3) ^ ((c1 >> 3) & 3)) << 3);
    const unsigned short* gA0 = A + (size_t)(bm * 128 + r0) * lda + kt0 + col0;
    const unsigned short* gA1 = A + (size_t)(bm * 128 + r1) * lda + kt0 + col1;
    const unsigned short* gB0 = B + (size_t)(bn * 128 + r0) * ldb + kt0 + col0;
    const unsigned short* gB1 = B + (size_t)(bn * 128 + r1) * ldb + kt0 + col1;

    auto STAGE = [&](int buf, int tt) {
        char* d = lds + buf * 16384 + w * 2048;
        const int o = tt * 32;
        gld_lds16(gA0 + o, d);
        gld_lds16(gA1 + o, d + 1024);
        gld_lds16(gB0 + o, d + 8192);
        gld_lds16(gB1 + o, d + 8192 + 1024);
    };

    f32x4 acc[4][4] = {};

    const int lr = l & 15, Q = l >> 4;
    const int sw = ((Q ^ ((lr >> 1) & 3)) << 4);
    const int lrA = (wr * 64 + lr) * 64 + sw;
    const int lrB = 8192 + (wc * 64 + lr) * 64 + sw;

    STAGE(0, 0);
    VMW0();
    SBAR();

    #pragma unroll
    for (int tt = 0; tt < NT; ++tt) {
        const int cur = tt & 1;
        const bool more = (tt + 1 < NT);
        if (more) STAGE(cur ^ 1, tt + 1);
        __builtin_amdgcn_sched_barrier(0);

        const char* lb = lds + cur * 16384;
        bf16x8 af[4], bf[4];
        #pragma unroll
        for (int m = 0; m < 4; ++m) af[m] = *(const bf16x8*)(lb + lrA + m * 1024);
        #pragma unroll
        for (int n = 0; n < 4; ++n) bf[n] = *(const bf16x8*)(lb + lrB + n * 1024);

        __builtin_amdgcn_s_setprio(1);
        #pragma unroll
        for (int m = 0; m < 4; ++m)
            #pragma unroll
            for (int n = 0; n < 4; ++n)
                acc[m][n] = __builtin_amdgcn_mfma_f32_16x16x32_bf16(af[m], bf[n], acc[m][n], 0, 0, 0);
        __builtin_amdgcn_s_setprio(0);

        if (more) {
            VMW0();
            SBAR();
        }
    }

    const int rbase = bm * 128 + wr * 64;
    const int cbase = bn * 128 + wc * 64;
    const int g4 = Q * 4;

    if constexpr (EPI == 2) {
        unsigned short* C = (unsigned short*)Cout + (size_t)blockIdx.z * 524288;
        #pragma unroll
        for (int m = 0; m < 4; ++m)
            #pragma unroll
            for (int n = 0; n < 4; ++n)
                #pragma unroll
                for (int j = 0; j < 4; ++j) {
                    int rrow = rbase + m * 16 + g4 + j;
                    int ccol = cbase + n * 16 + lr;
                    C[(size_t)rrow * ldc + ccol] = f2b(acc[m][n][j]);
                }
    } else {
        if (bn < 4) {
            #pragma unroll
            for (int m = 0; m < 4; ++m)
                #pragma unroll
                for (int j = 0; j < 4; ++j) {
                    int rrow = rbase + m * 16 + g4 + j;
                    float p = 0.f;
                    #pragma unroll
                    for (int n = 0; n < 4; ++n) {
                        float qv = b2f(Qb[(size_t)rrow * 512 + cbase + n * 16 + lr]);
                        p += acc[m][n][j] * qv;
                    }
                    p += __shfl_xor(p, 1);
                    p += __shfl_xor(p, 2);
                    p += __shfl_xor(p, 4);
                    p += __shfl_xor(p, 8);
                    if (lr == 0) atomicAdd(&nrm[rrow], p);
                }
        } else {
            unsigned short* C = (unsigned short*)Cout;
            #pragma unroll
            for (int m = 0; m < 4; ++m)
                #pragma unroll
                for (int n = 0; n < 4; ++n)
                    #pragma unroll
                    for (int j = 0; j < 4; ++j) {
                        int rrow = rbase + m * 16 + g4 + j;
                        int ccol = cbase - 512 + n * 16 + lr;
                        C[(size_t)rrow * ldc + ccol] = f2b(acc[m][n][j]);
                    }
        }
    }
}

// ---------------- GHt split-K reduce (bf16 partials) + bf16 cast ----------------
__global__ void reduce_gh(const unsigned short* __restrict__ part, unsigned short* __restrict__ ght) {
    int i = blockIdx.x * 256 + threadIdx.x;
    float4 s = {0.f, 0.f, 0.f, 0.f};
    #pragma unroll
    for (int z = 0; z < 16; ++z) {
        ushort4 v = ((const ushort4*)(part + (size_t)z * 524288))[i];
        s.x += b2f(v.x); s.y += b2f(v.y); s.z += b2f(v.z); s.w += b2f(v.w);
    }
    ushort4 o;
    o.x = f2b(s.x); o.y = f2b(s.y); o.z = f2b(s.z); o.w = f2b(s.w);
    ((ushort4*)ght)[i] = o;
}

// ---------------- final: out = U * rsqrt(max(sqrt(nrm), eps)) ----------------
__global__ void final_norm(const unsigned short* __restrict__ U16, const float* __restrict__ nrm,
                           float* __restrict__ out) {
    int i = blockIdx.x * 256 + threadIdx.x;
    ushort4 u = ((const ushort4*)U16)[i];
    int row = i >> 7;
    float inv = 1.0f / fmaxf(sqrtf(nrm[row]), 1e-12f);
    float4 o;
    o.x = b2f(u.x) * inv; o.y = b2f(u.y) * inv; o.z = b2f(u.z) * inv; o.w = b2f(u.w) * inv;
    ((float4*)out)[i] = o;
}

extern "C" void kernel_launch(void* const* d_in, const int* in_sizes, int n_in,
                              void* d_out, int out_size, void* d_ws, size_t ws_size,
                              hipStream_t stream) {
    const float* x  = (const float*)d_in[0];
    const float* Wq = (const float*)d_in[1];
    const float* bq = (const float*)d_in[2];
    const float* Wk = (const float*)d_in[3];
    const float* bk = (const float*)d_in[4];
    const float* Wv = (const float*)d_in[5];
    const float* bv = (const float*)d_in[6];
    float* out = (float*)d_out;

    char* ws = (char*)d_ws;
    size_t off = 0;
    auto alloc = [&](size_t bytes) -> void* {
        void* p = ws + off;
        off = (off + bytes + 255) & ~(size_t)255;
        return p;
    };

    unsigned short* xb   = (unsigned short*)alloc((size_t)NTOK * DIM * 2);
    unsigned short* Wb   = (unsigned short*)alloc((size_t)QKVW * DIM * 2);
    float*          bc   = (float*)alloc(QKVW * 4);
    unsigned short* Qb   = (unsigned short*)alloc((size_t)NTOK * DIM * 2);
    unsigned short* KVt  = (unsigned short*)alloc((size_t)1024 * NTOK * 2);
    unsigned short* GHp  = (unsigned short*)alloc((size_t)16 * 1024 * 512 * 2);
    unsigned short* GHt  = (unsigned short*)alloc((size_t)1024 * 512 * 2);
    unsigned short* U16  = (unsigned short*)alloc((size_t)NTOK * DIM * 2);
    float*          nrm  = (float*)alloc(NTOK * 4);

    // converts + zero nrm
    f2b_kernel<<<(NTOK * DIM / 4 + 255) / 256, 256, 0, stream>>>(x, xb, NTOK * DIM / 4);
    f2b_kernel<<<(DIM * DIM / 4 + 255) / 256, 256, 0, stream>>>(Wq, Wb, DIM * DIM / 4);
    f2b_kernel<<<(DIM * DIM / 4 + 255) / 256, 256, 0, stream>>>(Wk, Wb + DIM * DIM, DIM * DIM / 4);
    f2b_kernel<<<(DIM * DIM / 4 + 255) / 256, 256, 0, stream>>>(Wv, Wb + 2 * DIM * DIM, DIM * DIM / 4);
    bias_concat<<<6, 256, 0, stream>>>(bq, bk, bv, bc);
    hipMemsetAsync(nrm, 0, NTOK * 4, stream);

    // QKV: Q -> Qb row-major; K/V -> KVt transposed (fused epilogue)
    gemm_qkv<6, 16><<<dim3(QKVW / 256, NTOK / 128), 256, 0, stream>>>(
        xb, DIM, Wb, DIM, Qb, KVt, bc);

    // GHt partials (bf16): GHt = KVt @ Kt^T   [1024 x 512], K=8192 split 16
    gemm7<2, 0, 16><<<dim3(512 / 128, 1024 / 128, 16), 256, 0, stream>>>(
        KVt, NTOK, KVt, NTOK, GHp, 512, nullptr, nullptr);

    // GHt(bf16) = sum_z GHp[z]   [1024 x 512]
    reduce_gh<<<512, 256, 0, stream>>>(GHp, GHt);

    // TU = Q @ GHt^T: T-cols (bn<4) fused into nrm rowdot; U stored bf16
    gemm7<4, 8, 16><<<dim3(1024 / 128, NTOK / 128), 256, 0, stream>>>(
        Qb, 512, GHt, 512, U16, DIM, Qb, nrm);

    // out = U * rsqrt(max(sqrt(nrm), eps))
    final_norm<<<NTOK * DIM / 4 / 256, 256, 0, stream>>>(U16, nrm, out);
}

// Round 20
// 80.501 us; speedup vs baseline: 1.2217x; 1.0322x over previous
//
#include <hip/hip_runtime.h>
#include <hip/hip_bf16.h>
#include <stdint.h>

#define NTOK 8192
#define DIM  512
#define QKVW 1536

typedef __attribute__((ext_vector_type(8))) short bf16x8;
typedef __attribute__((ext_vector_type(4))) float f32x4;

static __device__ __forceinline__ unsigned short f2b(float f) {
    union { float f; unsigned int u; } v; v.f = f;
    unsigned int r = v.u + 0x7fffu + ((v.u >> 16) & 1u);
    return (unsigned short)(r >> 16);
}

static __device__ __forceinline__ float b2f(unsigned short u) {
    union { unsigned int i; float f; } v; v.i = ((unsigned int)u) << 16;
    return v.f;
}

static __device__ __forceinline__ void gld_lds16(const void* g, void* l) {
    __builtin_amdgcn_global_load_lds(
        (__attribute__((address_space(1))) void*)(uintptr_t)g,
        (__attribute__((address_space(3))) void*)(uintptr_t)l,
        16, 0, 0);
}

#define SBAR() do { __builtin_amdgcn_sched_barrier(0); __builtin_amdgcn_s_barrier(); __builtin_amdgcn_sched_barrier(0); } while (0)
#define VMW0() do { __builtin_amdgcn_sched_barrier(0); asm volatile("s_waitcnt vmcnt(0)" ::: "memory"); __builtin_amdgcn_sched_barrier(0); } while (0)
#define LGKM0() do { __builtin_amdgcn_sched_barrier(0); asm volatile("s_waitcnt lgkmcnt(0)" ::: "memory"); __builtin_amdgcn_sched_barrier(0); } while (0)

// ---------------- converts ----------------

__global__ void f2b_kernel(const float* __restrict__ src, unsigned short* __restrict__ dst, int n4) {
    int i = blockIdx.x * blockDim.x + threadIdx.x;
    if (i < n4) {
        float4 f = ((const float4*)src)[i];
        ushort4 o;
        o.x = f2b(f.x); o.y = f2b(f.y); o.z = f2b(f.z); o.w = f2b(f.w);
        ((ushort4*)dst)[i] = o;
    }
}

__global__ void f2b_w3(const float* __restrict__ w0, const float* __restrict__ w1,
                       const float* __restrict__ w2, unsigned short* __restrict__ dst) {
    int which = blockIdx.y;
    const float* src = (which == 0) ? w0 : (which == 1) ? w1 : w2;
    int i = blockIdx.x * 256 + threadIdx.x;   // 262144/4 = 65536 -> 256 blocks
    float4 f = ((const float4*)src)[i];
    ushort4 o;
    o.x = f2b(f.x); o.y = f2b(f.y); o.z = f2b(f.z); o.w = f2b(f.w);
    ((ushort4*)(dst + (size_t)which * 262144))[i] = o;
}

__global__ void bias_concat(const float* __restrict__ bq, const float* __restrict__ bk,
                            const float* __restrict__ bv, float* __restrict__ bc) {
    int i = blockIdx.x * blockDim.x + threadIdx.x;
    if (i < 512)       bc[i] = bq[i];
    else if (i < 1024) bc[i] = bk[i - 512];
    else if (i < 1536) bc[i] = bv[i - 1024];
}

// ------- QKV GEMM 128x128 (3 blocks/CU balanced): Q -> Qb; K/V -> KVt transposed -------
// Core = r7-verified 2-phase 128x128. Epilogue bn>=4: per-wave LDS transpose in
// two 32-col half-passes ([32c][72r] pad, 4.6KB/wave), coalesced 8B/lane stores.
template <int CH, int NT>
__global__ __launch_bounds__(256, 4) void gemm_qkv2(
    const unsigned short* __restrict__ A, int lda,
    const unsigned short* __restrict__ B, int ldb,
    unsigned short* __restrict__ Qb,
    unsigned short* __restrict__ KVt,
    const float* __restrict__ bias) {

    __shared__ __align__(16) char lds[32768];

    const int t = threadIdx.x;
    const int l = t & 63, w = t >> 6;
    const int wr = w >> 1, wc = w & 1;

    const int gx = gridDim.x;
    const int nbm = gridDim.y >> 3;
    const int bid = blockIdx.y * gx + blockIdx.x;
    const int xcd = bid & 7, qq = bid >> 3;
    const int win = nbm * CH;
    const int grp = qq / win, rr = qq % win;
    const int bm = xcd * nbm + rr / CH;
    const int bn = grp * CH + rr % CH;

    const int c0 = w * 128 + l;
    const int c1 = c0 + 64;
    const int r0 = c0 >> 2, r1 = c1 >> 2;
    const int col0 = (((c0 & 3) ^ ((c0 >> 3) & 3)) << 3);
    const int col1 = (((c1 & 3) ^ ((c1 >> 3) & 3)) << 3);
    const unsigned short* gA0 = A + (size_t)(bm * 128 + r0) * lda + col0;
    const unsigned short* gA1 = A + (size_t)(bm * 128 + r1) * lda + col1;
    const unsigned short* gB0 = B + (size_t)(bn * 128 + r0) * ldb + col0;
    const unsigned short* gB1 = B + (size_t)(bn * 128 + r1) * ldb + col1;

    auto STAGE = [&](int buf, int tt) {
        char* d = lds + buf * 16384 + w * 2048;
        const int o = tt * 32;
        gld_lds16(gA0 + o, d);
        gld_lds16(gA1 + o, d + 1024);
        gld_lds16(gB0 + o, d + 8192);
        gld_lds16(gB1 + o, d + 8192 + 1024);
    };

    f32x4 acc[4][4] = {};

    const int lr = l & 15, Q = l >> 4;
    const int sw = ((Q ^ ((lr >> 1) & 3)) << 4);
    const int lrA = (wr * 64 + lr) * 64 + sw;
    const int lrB = 8192 + (wc * 64 + lr) * 64 + sw;

    STAGE(0, 0);
    VMW0();
    SBAR();

    #pragma unroll
    for (int tt = 0; tt < NT; ++tt) {
        const int cur = tt & 1;
        const bool more = (tt + 1 < NT);
        if (more) STAGE(cur ^ 1, tt + 1);
        __builtin_amdgcn_sched_barrier(0);

        const char* lb = lds + cur * 16384;
        bf16x8 af[4], bf[4];
        #pragma unroll
        for (int m = 0; m < 4; ++m) af[m] = *(const bf16x8*)(lb + lrA + m * 1024);
        #pragma unroll
        for (int n = 0; n < 4; ++n) bf[n] = *(const bf16x8*)(lb + lrB + n * 1024);

        __builtin_amdgcn_s_setprio(1);
        #pragma unroll
        for (int m = 0; m < 4; ++m)
            #pragma unroll
            for (int n = 0; n < 4; ++n)
                acc[m][n] = __builtin_amdgcn_mfma_f32_16x16x32_bf16(af[m], bf[n], acc[m][n], 0, 0, 0);
        __builtin_amdgcn_s_setprio(0);

        if (more) {
            VMW0();
            SBAR();
        }
    }

    const int rbase = bm * 128 + wr * 64;
    const int cbase = bn * 128 + wc * 64;
    const int g4 = Q * 4;

    if (bn < 4) {
        // Q region: row-major into Qb (ldc 512)
        #pragma unroll
        for (int m = 0; m < 4; ++m)
            #pragma unroll
            for (int n = 0; n < 4; ++n)
                #pragma unroll
                for (int j = 0; j < 4; ++j) {
                    int rrow = rbase + m * 16 + g4 + j;
                    int ccol = cbase + n * 16 + lr;
                    Qb[(size_t)rrow * 512 + ccol] = f2b(acc[m][n][j] + bias[ccol]);
                }
    } else {
        // K/V region: per-wave LDS transpose, two 32-col half-passes
        SBAR();   // all waves done reading staging buffers
        unsigned short* wt = (unsigned short*)(lds + w * 8192);   // [32c][72r]
        #pragma unroll
        for (int p = 0; p < 2; ++p) {
            #pragma unroll
            for (int m = 0; m < 4; ++m)
                #pragma unroll
                for (int q2 = 0; q2 < 2; ++q2) {
                    int n = 2 * p + q2;
                    int cloc = q2 * 16 + lr;                  // 0..31
                    int ccol = cbase + n * 16 + lr;           // global col (512..1535)
                    unsigned short s0 = f2b(acc[m][n][0] + bias[ccol]);
                    unsigned short s1 = f2b(acc[m][n][1] + bias[ccol]);
                    unsigned short s2 = f2b(acc[m][n][2] + bias[ccol]);
                    unsigned short s3 = f2b(acc[m][n][3] + bias[ccol]);
                    uint2 v;
                    v.x = (unsigned int)s0 | ((unsigned int)s1 << 16);
                    v.y = (unsigned int)s2 | ((unsigned int)s3 << 16);
                    *(uint2*)(wt + cloc * 72 + m * 16 + g4) = v;
                }
            LGKM0();
            const int kvb = cbase - 512 + 32 * p;
            #pragma unroll
            for (int cc = 0; cc < 8; ++cc) {
                int cloc = cc * 4 + Q;
                uint2 v = *(const uint2*)(wt + cloc * 72 + lr * 4);
                *(uint2*)&KVt[(size_t)(kvb + cloc) * NTOK + rbase + lr * 4] = v;
            }
            if (p == 0) LGKM0();
        }
    }
}

// ---------------- 2-phase 128x128 bf16 GEMM (r7-verified core), 4 blocks/CU ----------------
// EPI 2: bf16 partial store at z-offset (GH)
// EPI 4: fused TU: bn<4 -> rowdot(T,Q) atomicAdd nrm; bn>=4 -> bf16 U store
template <int EPI, int CH, int NT>
__global__ __launch_bounds__(256, 4) void gemm7(
    const unsigned short* __restrict__ A, int lda,
    const unsigned short* __restrict__ B, int ldb,
    void* __restrict__ Cout, int ldc,
    const unsigned short* __restrict__ Qb,
    float* __restrict__ nrm) {

    __shared__ __align__(16) char lds[32768];

    const int t = threadIdx.x;
    const int l = t & 63, w = t >> 6;
    const int wr = w >> 1, wc = w & 1;

    int bm, bn;
    if constexpr (CH == 0) {
        bm = blockIdx.y; bn = blockIdx.x;
    } else {
        const int gx = gridDim.x;
        const int nbm = gridDim.y >> 3;
        const int bid = blockIdx.y * gx + blockIdx.x;
        const int xcd = bid & 7, qq = bid >> 3;
        const int win = nbm * CH;
        const int grp = qq / win, rr = qq % win;
        bm = xcd * nbm + rr / CH;
        bn = grp * CH + rr % CH;
    }

    const int kt0 = blockIdx.z * (NT * 32);

    const int c0 = w * 128 + l;
    const int c1 = c0 + 64;
    const int r0 = c0 >> 2, r1 = c1 >> 2;
    const int col0 = (((c0 & 3) ^ ((c0 >> 3) & 3)) << 3);
    const int col1 = (((c1 & 3) ^ ((c1 >> 3) & 3)) << 3);
    const unsigned short* gA0 = A + (size_t)(bm * 128 + r0) * lda + kt0 + col0;
    const unsigned short* gA1 = A + (size_t)(bm * 128 + r1) * lda + kt0 + col1;
    const unsigned short* gB0 = B + (size_t)(bn * 128 + r0) * ldb + kt0 + col0;
    const unsigned short* gB1 = B + (size_t)(bn * 128 + r1) * ldb + kt0 + col1;

    auto STAGE = [&](int buf, int tt) {
        char* d = lds + buf * 16384 + w * 2048;
        const int o = tt * 32;
        gld_lds16(gA0 + o, d);
        gld_lds16(gA1 + o, d + 1024);
        gld_lds16(gB0 + o, d + 8192);
        gld_lds16(gB1 + o, d + 8192 + 1024);
    };

    f32x4 acc[4][4] = {};

    const int lr = l & 15, Q = l >> 4;
    const int sw = ((Q ^ ((lr >> 1) & 3)) << 4);
    const int lrA = (wr * 64 + lr) * 64 + sw;
    const int lrB = 8192 + (wc * 64 + lr) * 64 + sw;

    STAGE(0, 0);
    VMW0();
    SBAR();

    #pragma unroll
    for (int tt = 0; tt < NT; ++tt) {
        const int cur = tt & 1;
        const bool more = (tt + 1 < NT);
        if (more) STAGE(cur ^ 1, tt + 1);
        __builtin_amdgcn_sched_barrier(0);

        const char* lb = lds + cur * 16384;
        bf16x8 af[4], bf[4];
        #pragma unroll
        for (int m = 0; m < 4; ++m) af[m] = *(const bf16x8*)(lb + lrA + m * 1024);
        #pragma unroll
        for (int n = 0; n < 4; ++n) bf[n] = *(const bf16x8*)(lb + lrB + n * 1024);

        __builtin_amdgcn_s_setprio(1);
        #pragma unroll
        for (int m = 0; m < 4; ++m)
            #pragma unroll
            for (int n = 0; n < 4; ++n)
                acc[m][n] = __builtin_amdgcn_mfma_f32_16x16x32_bf16(af[m], bf[n], acc[m][n], 0, 0, 0);
        __builtin_amdgcn_s_setprio(0);

        if (more) {
            VMW0();
            SBAR();
        }
    }

    const int rbase = bm * 128 + wr * 64;
    const int cbase = bn * 128 + wc * 64;
    const int g4 = Q * 4;

    if constexpr (EPI == 2) {
        unsigned short* C = (unsigned short*)Cout + (size_t)blockIdx.z * 524288;
        #pragma unroll
        for (int m = 0; m < 4; ++m)
            #pragma unroll
            for (int n = 0; n < 4; ++n)
                #pragma unroll
                for (int j = 0; j < 4; ++j) {
                    int rrow = rbase + m * 16 + g4 + j;
                    int ccol = cbase + n * 16 + lr;
                    C[(size_t)rrow * ldc + ccol] = f2b(acc[m][n][j]);
                }
    } else {
        if (bn < 4) {
            #pragma unroll
            for (int m = 0; m < 4; ++m)
                #pragma unroll
                for (int j = 0; j < 4; ++j) {
                    int rrow = rbase + m * 16 + g4 + j;
                    float p = 0.f;
                    #pragma unroll
                    for (int n = 0; n < 4; ++n) {
                        float qv = b2f(Qb[(size_t)rrow * 512 + cbase + n * 16 + lr]);
                        p += acc[m][n][j] * qv;
                    }
                    p += __shfl_xor(p, 1);
                    p += __shfl_xor(p, 2);
                    p += __shfl_xor(p, 4);
                    p += __shfl_xor(p, 8);
                    if (lr == 0) atomicAdd(&nrm[rrow], p);
                }
        } else {
            unsigned short* C = (unsigned short*)Cout;
            #pragma unroll
            for (int m = 0; m < 4; ++m)
                #pragma unroll
                for (int n = 0; n < 4; ++n)
                    #pragma unroll
                    for (int j = 0; j < 4; ++j) {
                        int rrow = rbase + m * 16 + g4 + j;
                        int ccol = cbase - 512 + n * 16 + lr;
                        C[(size_t)rrow * ldc + ccol] = f2b(acc[m][n][j]);
                    }
        }
    }
}

// ---------------- GHt split-K reduce (bf16 partials) + bf16 cast ----------------
__global__ void reduce_gh(const unsigned short* __restrict__ part, unsigned short* __restrict__ ght) {
    int i = blockIdx.x * 256 + threadIdx.x;
    float4 s = {0.f, 0.f, 0.f, 0.f};
    #pragma unroll
    for (int z = 0; z < 16; ++z) {
        ushort4 v = ((const ushort4*)(part + (size_t)z * 524288))[i];
        s.x += b2f(v.x); s.y += b2f(v.y); s.z += b2f(v.z); s.w += b2f(v.w);
    }
    ushort4 o;
    o.x = f2b(s.x); o.y = f2b(s.y); o.z = f2b(s.z); o.w = f2b(s.w);
    ((ushort4*)ght)[i] = o;
}

// ---------------- final: out = U * rsqrt(max(sqrt(nrm), eps)) ----------------
__global__ void final_norm(const unsigned short* __restrict__ U16, const float* __restrict__ nrm,
                           float* __restrict__ out) {
    int i = blockIdx.x * 256 + threadIdx.x;
    ushort4 u = ((const ushort4*)U16)[i];
    int row = i >> 7;
    float inv = 1.0f / fmaxf(sqrtf(nrm[row]), 1e-12f);
    float4 o;
    o.x = b2f(u.x) * inv; o.y = b2f(u.y) * inv; o.z = b2f(u.z) * inv; o.w = b2f(u.w) * inv;
    ((float4*)out)[i] = o;
}

extern "C" void kernel_launch(void* const* d_in, const int* in_sizes, int n_in,
                              void* d_out, int out_size, void* d_ws, size_t ws_size,
                              hipStream_t stream) {
    const float* x  = (const float*)d_in[0];
    const float* Wq = (const float*)d_in[1];
    const float* bq = (const float*)d_in[2];
    const float* Wk = (const float*)d_in[3];
    const float* bk = (const float*)d_in[4];
    const float* Wv = (const float*)d_in[5];
    const float* bv = (const float*)d_in[6];
    float* out = (float*)d_out;

    char* ws = (char*)d_ws;
    size_t off = 0;
    auto alloc = [&](size_t bytes) -> void* {
        void* p = ws + off;
        off = (off + bytes + 255) & ~(size_t)255;
        return p;
    };

    unsigned short* xb   = (unsigned short*)alloc((size_t)NTOK * DIM * 2);
    unsigned short* Wb   = (unsigned short*)alloc((size_t)QKVW * DIM * 2);
    float*          bc   = (float*)alloc(QKVW * 4);
    unsigned short* Qb   = (unsigned short*)alloc((size_t)NTOK * DIM * 2);
    unsigned short* KVt  = (unsigned short*)alloc((size_t)1024 * NTOK * 2);
    unsigned short* GHp  = (unsigned short*)alloc((size_t)16 * 1024 * 512 * 2);
    unsigned short* GHt  = (unsigned short*)alloc((size_t)1024 * 512 * 2);
    unsigned short* U16  = (unsigned short*)alloc((size_t)NTOK * DIM * 2);
    float*          nrm  = (float*)alloc(NTOK * 4);

    // converts + zero nrm
    f2b_kernel<<<(NTOK * DIM / 4 + 255) / 256, 256, 0, stream>>>(x, xb, NTOK * DIM / 4);
    f2b_w3<<<dim3(DIM * DIM / 4 / 256, 3), 256, 0, stream>>>(Wq, Wk, Wv, Wb);
    bias_concat<<<6, 256, 0, stream>>>(bq, bk, bv, bc);
    hipMemsetAsync(nrm, 0, NTOK * 4, stream);

    // QKV: Q -> Qb row-major; K/V -> KVt transposed. 128^2 tile, 768 blocks = 3/CU
    gemm_qkv2<12, 16><<<dim3(QKVW / 128, NTOK / 128), 256, 0, stream>>>(
        xb, DIM, Wb, DIM, Qb, KVt, bc);

    // GHt partials (bf16): GHt = KVt @ Kt^T   [1024 x 512], K=8192 split 16
    gemm7<2, 0, 16><<<dim3(512 / 128, 1024 / 128, 16), 256, 0, stream>>>(
        KVt, NTOK, KVt, NTOK, GHp, 512, nullptr, nullptr);

    // GHt(bf16) = sum_z GHp[z]   [1024 x 512]
    reduce_gh<<<512, 256, 0, stream>>>(GHp, GHt);

    // TU = Q @ GHt^T: T-cols (bn<4) fused into nrm rowdot; U stored bf16
    gemm7<4, 8, 16><<<dim3(1024 / 128, NTOK / 128), 256, 0, stream>>>(
        Qb, 512, GHt, 512, U16, DIM, Qb, nrm);

    // out = U * rsqrt(max(sqrt(nrm), eps))
    final_norm<<<NTOK * DIM / 4 / 256, 256, 0, stream>>>(U16, nrm, out);
}

// Round 21
// 71.435 us; speedup vs baseline: 1.3767x; 1.1269x over previous
//
#include <hip/hip_runtime.h>
#include <hip/hip_bf16.h>
#include <stdint.h>

#define NTOK 8192
#define DIM  512
#define QKVW 1536

typedef __attribute__((ext_vector_type(8))) short bf16x8;
typedef __attribute__((ext_vector_type(4))) float f32x4;

static __device__ __forceinline__ unsigned short f2b(float f) {
    union { float f; unsigned int u; } v; v.f = f;
    unsigned int r = v.u + 0x7fffu + ((v.u >> 16) & 1u);
    return (unsigned short)(r >> 16);
}

static __device__ __forceinline__ float b2f(unsigned short u) {
    union { unsigned int i; float f; } v; v.i = ((unsigned int)u) << 16;
    return v.f;
}

static __device__ __forceinline__ void gld_lds16(const void* g, void* l) {
    __builtin_amdgcn_global_load_lds(
        (__attribute__((address_space(1))) void*)(uintptr_t)g,
        (__attribute__((address_space(3))) void*)(uintptr_t)l,
        16, 0, 0);
}

#define SBAR() do { __builtin_amdgcn_sched_barrier(0); __builtin_amdgcn_s_barrier(); __builtin_amdgcn_sched_barrier(0); } while (0)
#define VMW0() do { __builtin_amdgcn_sched_barrier(0); asm volatile("s_waitcnt vmcnt(0)" ::: "memory"); __builtin_amdgcn_sched_barrier(0); } while (0)
#define LGKM0() do { __builtin_amdgcn_sched_barrier(0); asm volatile("s_waitcnt lgkmcnt(0)" ::: "memory"); __builtin_amdgcn_sched_barrier(0); } while (0)

// ---------------- fused prep: x->bf16, W->bf16, bias concat, nrm zero ----------------
__global__ void prep(const float* __restrict__ x,
                     const float* __restrict__ Wq, const float* __restrict__ Wk,
                     const float* __restrict__ Wv,
                     const float* __restrict__ bq, const float* __restrict__ bk,
                     const float* __restrict__ bv,
                     unsigned short* __restrict__ xb, unsigned short* __restrict__ Wb,
                     float* __restrict__ bc, float* __restrict__ nrm) {
    int b = blockIdx.x, t = threadIdx.x;
    if (b < 4096) {
        int i = b * 256 + t;                       // over 1048576 float4
        float4 f = ((const float4*)x)[i];
        ushort4 o;
        o.x = f2b(f.x); o.y = f2b(f.y); o.z = f2b(f.z); o.w = f2b(f.w);
        ((ushort4*)xb)[i] = o;
    } else if (b < 4864) {
        int bb = b - 4096;
        int which = bb >> 8;
        const float* src = (which == 0) ? Wq : (which == 1) ? Wk : Wv;
        int i = (bb & 255) * 256 + t;              // over 65536 float4
        float4 f = ((const float4*)src)[i];
        ushort4 o;
        o.x = f2b(f.x); o.y = f2b(f.y); o.z = f2b(f.z); o.w = f2b(f.w);
        ((ushort4*)(Wb + (size_t)which * 262144))[i] = o;
    } else if (b < 4870) {
        int i = (b - 4864) * 256 + t;              // over 1536
        if (i < 512)       bc[i] = bq[i];
        else if (i < 1024) bc[i] = bk[i - 512];
        else               bc[i] = bv[i - 1024];
    } else {
        int i = (b - 4870) * 256 + t;              // over 2048 float4 (nrm 8192 f32)
        float4 z = {0.f, 0.f, 0.f, 0.f};
        ((float4*)nrm)[i] = z;
    }
}

// ============ BK=64 2-phase 128x128 bf16 GEMM core (NT slots of K=64) ============
// LDS 64KB = 2 bufs x (A 16KB | B 16KB). Row = 128B (64 bf16) = 8 slots of 16B.
// Staging chunk c = i*256+t: LDS byte c*16 (linear dest), row = c>>3, slot = c&7,
// source sub-block p = (c&7) ^ ((row>>1)&7)  -> per row 8 lanes cover the full
// 128B line (coalesced); readback bank = (slot*4+j)%32, uniform 8/bank (free).
// Frag read: kq = Q (k 0-31) and Q+4 (k 32-63) at slot kq ^ ((lr>>1)&7).
// grid-limited occupancy (2-3 blocks/CU) unaffected by the 64KB LDS.

// ------- QKV: Q rows -> Qb[8192x512]; K/V -> KVt[1024x8192] transposed -------
template <int CH, int NT>
__global__ __launch_bounds__(256, 2) void gemm_qkv3(
    const unsigned short* __restrict__ A, int lda,
    const unsigned short* __restrict__ B, int ldb,
    unsigned short* __restrict__ Qb,
    unsigned short* __restrict__ KVt,
    const float* __restrict__ bias) {

    __shared__ __align__(16) char lds[65536];

    const int t = threadIdx.x;
    const int l = t & 63, w = t >> 6;
    const int wr = w >> 1, wc = w & 1;

    const int gx = gridDim.x;
    const int nbm = gridDim.y >> 3;
    const int bid = blockIdx.y * gx + blockIdx.x;
    const int xcd = bid & 7, qq = bid >> 3;
    const int win = nbm * CH;
    const int grp = qq / win, rr = qq % win;
    const int bm = xcd * nbm + rr / CH;
    const int bn = grp * CH + rr % CH;

    const unsigned short* sA[4];
    const unsigned short* sB[4];
    #pragma unroll
    for (int i = 0; i < 4; ++i) {
        int c = i * 256 + t;
        int row = c >> 3;
        int p = (c & 7) ^ ((row >> 1) & 7);
        sA[i] = A + (size_t)(bm * 128 + row) * lda + p * 8;
        sB[i] = B + (size_t)(bn * 128 + row) * ldb + p * 8;
    }

    auto STAGE = [&](int buf, int tt) {
        char* d = lds + buf * 32768 + w * 1024;
        const int o = tt * 64;
        #pragma unroll
        for (int i = 0; i < 4; ++i) {
            gld_lds16(sA[i] + o, d + i * 4096);
            gld_lds16(sB[i] + o, d + 16384 + i * 4096);
        }
    };

    f32x4 acc[4][4] = {};

    const int lr = l & 15, Q = l >> 4;
    const int g = (lr >> 1) & 7;
    const int sw0 = ((Q ^ g) << 4), sw1 = (((Q + 4) ^ g) << 4);
    const int lrA = (wr * 64 + lr) * 128;
    const int lrB = 16384 + (wc * 64 + lr) * 128;

    STAGE(0, 0);
    VMW0();
    SBAR();

    #pragma unroll
    for (int tt = 0; tt < NT; ++tt) {
        const int cur = tt & 1;
        const bool more = (tt + 1 < NT);
        if (more) STAGE(cur ^ 1, tt + 1);
        __builtin_amdgcn_sched_barrier(0);

        const char* lb = lds + cur * 32768;
        bf16x8 af[4][2], bf[4][2];
        #pragma unroll
        for (int m = 0; m < 4; ++m) {
            af[m][0] = *(const bf16x8*)(lb + lrA + m * 2048 + sw0);
            af[m][1] = *(const bf16x8*)(lb + lrA + m * 2048 + sw1);
        }
        #pragma unroll
        for (int n = 0; n < 4; ++n) {
            bf[n][0] = *(const bf16x8*)(lb + lrB + n * 2048 + sw0);
            bf[n][1] = *(const bf16x8*)(lb + lrB + n * 2048 + sw1);
        }

        __builtin_amdgcn_s_setprio(1);
        #pragma unroll
        for (int m = 0; m < 4; ++m)
            #pragma unroll
            for (int n = 0; n < 4; ++n) {
                acc[m][n] = __builtin_amdgcn_mfma_f32_16x16x32_bf16(af[m][0], bf[n][0], acc[m][n], 0, 0, 0);
                acc[m][n] = __builtin_amdgcn_mfma_f32_16x16x32_bf16(af[m][1], bf[n][1], acc[m][n], 0, 0, 0);
            }
        __builtin_amdgcn_s_setprio(0);

        if (more) {
            VMW0();
            SBAR();
        }
    }

    const int rbase = bm * 128 + wr * 64;
    const int cbase = bn * 128 + wc * 64;
    const int g4 = Q * 4;

    if (bn < 4) {
        // Q region: row-major into Qb (ldc 512)
        #pragma unroll
        for (int m = 0; m < 4; ++m)
            #pragma unroll
            for (int n = 0; n < 4; ++n)
                #pragma unroll
                for (int j = 0; j < 4; ++j) {
                    int rrow = rbase + m * 16 + g4 + j;
                    int ccol = cbase + n * 16 + lr;
                    Qb[(size_t)rrow * 512 + ccol] = f2b(acc[m][n][j] + bias[ccol]);
                }
    } else {
        // K/V region: per-wave LDS transpose, two 32-col half-passes (r19/r20-verified)
        SBAR();   // all waves done reading staging buffers
        unsigned short* wt = (unsigned short*)(lds + w * 8192);   // [32c][72r]
        #pragma unroll
        for (int p = 0; p < 2; ++p) {
            #pragma unroll
            for (int m = 0; m < 4; ++m)
                #pragma unroll
                for (int q2 = 0; q2 < 2; ++q2) {
                    int n = 2 * p + q2;
                    int cloc = q2 * 16 + lr;
                    int ccol = cbase + n * 16 + lr;
                    unsigned short s0 = f2b(acc[m][n][0] + bias[ccol]);
                    unsigned short s1 = f2b(acc[m][n][1] + bias[ccol]);
                    unsigned short s2 = f2b(acc[m][n][2] + bias[ccol]);
                    unsigned short s3 = f2b(acc[m][n][3] + bias[ccol]);
                    uint2 v;
                    v.x = (unsigned int)s0 | ((unsigned int)s1 << 16);
                    v.y = (unsigned int)s2 | ((unsigned int)s3 << 16);
                    *(uint2*)(wt + cloc * 72 + m * 16 + g4) = v;
                }
            LGKM0();
            const int kvb = cbase - 512 + 32 * p;
            #pragma unroll
            for (int cc = 0; cc < 8; ++cc) {
                int cloc = cc * 4 + Q;
                uint2 v = *(const uint2*)(wt + cloc * 72 + lr * 4);
                *(uint2*)&KVt[(size_t)(kvb + cloc) * NTOK + rbase + lr * 4] = v;
            }
            if (p == 0) LGKM0();
        }
    }
}

// ------- generic BK=64 GEMM: EPI 2 = bf16 partial store (GH); EPI 4 = fused TU -------
template <int EPI, int CH, int NT>
__global__ __launch_bounds__(256, 2) void gemm8b(
    const unsigned short* __restrict__ A, int lda,
    const unsigned short* __restrict__ B, int ldb,
    void* __restrict__ Cout, int ldc,
    const unsigned short* __restrict__ Qb,
    float* __restrict__ nrm) {

    __shared__ __align__(16) char lds[65536];

    const int t = threadIdx.x;
    const int l = t & 63, w = t >> 6;
    const int wr = w >> 1, wc = w & 1;

    int bm, bn;
    if constexpr (CH == 0) {
        bm = blockIdx.y; bn = blockIdx.x;
    } else {
        const int gx = gridDim.x;
        const int nbm = gridDim.y >> 3;
        const int bid = blockIdx.y * gx + blockIdx.x;
        const int xcd = bid & 7, qq = bid >> 3;
        const int win = nbm * CH;
        const int grp = qq / win, rr = qq % win;
        bm = xcd * nbm + rr / CH;
        bn = grp * CH + rr % CH;
    }

    const int kt0 = blockIdx.z * (NT * 64);

    const unsigned short* sA[4];
    const unsigned short* sB[4];
    #pragma unroll
    for (int i = 0; i < 4; ++i) {
        int c = i * 256 + t;
        int row = c >> 3;
        int p = (c & 7) ^ ((row >> 1) & 7);
        sA[i] = A + (size_t)(bm * 128 + row) * lda + kt0 + p * 8;
        sB[i] = B + (size_t)(bn * 128 + row) * ldb + kt0 + p * 8;
    }

    auto STAGE = [&](int buf, int tt) {
        char* d = lds + buf * 32768 + w * 1024;
        const int o = tt * 64;
        #pragma unroll
        for (int i = 0; i < 4; ++i) {
            gld_lds16(sA[i] + o, d + i * 4096);
            gld_lds16(sB[i] + o, d + 16384 + i * 4096);
        }
    };

    f32x4 acc[4][4] = {};

    const int lr = l & 15, Q = l >> 4;
    const int g = (lr >> 1) & 7;
    const int sw0 = ((Q ^ g) << 4), sw1 = (((Q + 4) ^ g) << 4);
    const int lrA = (wr * 64 + lr) * 128;
    const int lrB = 16384 + (wc * 64 + lr) * 128;

    STAGE(0, 0);
    VMW0();
    SBAR();

    #pragma unroll
    for (int tt = 0; tt < NT; ++tt) {
        const int cur = tt & 1;
        const bool more = (tt + 1 < NT);
        if (more) STAGE(cur ^ 1, tt + 1);
        __builtin_amdgcn_sched_barrier(0);

        const char* lb = lds + cur * 32768;
        bf16x8 af[4][2], bf[4][2];
        #pragma unroll
        for (int m = 0; m < 4; ++m) {
            af[m][0] = *(const bf16x8*)(lb + lrA + m * 2048 + sw0);
            af[m][1] = *(const bf16x8*)(lb + lrA + m * 2048 + sw1);
        }
        #pragma unroll
        for (int n = 0; n < 4; ++n) {
            bf[n][0] = *(const bf16x8*)(lb + lrB + n * 2048 + sw0);
            bf[n][1] = *(const bf16x8*)(lb + lrB + n * 2048 + sw1);
        }

        __builtin_amdgcn_s_setprio(1);
        #pragma unroll
        for (int m = 0; m < 4; ++m)
            #pragma unroll
            for (int n = 0; n < 4; ++n) {
                acc[m][n] = __builtin_amdgcn_mfma_f32_16x16x32_bf16(af[m][0], bf[n][0], acc[m][n], 0, 0, 0);
                acc[m][n] = __builtin_amdgcn_mfma_f32_16x16x32_bf16(af[m][1], bf[n][1], acc[m][n], 0, 0, 0);
            }
        __builtin_amdgcn_s_setprio(0);

        if (more) {
            VMW0();
            SBAR();
        }
    }

    const int rbase = bm * 128 + wr * 64;
    const int cbase = bn * 128 + wc * 64;
    const int g4 = Q * 4;

    if constexpr (EPI == 2) {
        unsigned short* C = (unsigned short*)Cout + (size_t)blockIdx.z * 524288;
        #pragma unroll
        for (int m = 0; m < 4; ++m)
            #pragma unroll
            for (int n = 0; n < 4; ++n)
                #pragma unroll
                for (int j = 0; j < 4; ++j) {
                    int rrow = rbase + m * 16 + g4 + j;
                    int ccol = cbase + n * 16 + lr;
                    C[(size_t)rrow * ldc + ccol] = f2b(acc[m][n][j]);
                }
    } else {
        if (bn < 4) {
            #pragma unroll
            for (int m = 0; m < 4; ++m)
                #pragma unroll
                for (int j = 0; j < 4; ++j) {
                    int rrow = rbase + m * 16 + g4 + j;
                    float p = 0.f;
                    #pragma unroll
                    for (int n = 0; n < 4; ++n) {
                        float qv = b2f(Qb[(size_t)rrow * 512 + cbase + n * 16 + lr]);
                        p += acc[m][n][j] * qv;
                    }
                    p += __shfl_xor(p, 1);
                    p += __shfl_xor(p, 2);
                    p += __shfl_xor(p, 4);
                    p += __shfl_xor(p, 8);
                    if (lr == 0) atomicAdd(&nrm[rrow], p);
                }
        } else {
            unsigned short* C = (unsigned short*)Cout;
            #pragma unroll
            for (int m = 0; m < 4; ++m)
                #pragma unroll
                for (int n = 0; n < 4; ++n)
                    #pragma unroll
                    for (int j = 0; j < 4; ++j) {
                        int rrow = rbase + m * 16 + g4 + j;
                        int ccol = cbase - 512 + n * 16 + lr;
                        C[(size_t)rrow * ldc + ccol] = f2b(acc[m][n][j]);
                    }
        }
    }
}

// ---------------- GHt split-K reduce (bf16 partials) + bf16 cast ----------------
__global__ void reduce_gh(const unsigned short* __restrict__ part, unsigned short* __restrict__ ght) {
    int i = blockIdx.x * 256 + threadIdx.x;
    float4 s = {0.f, 0.f, 0.f, 0.f};
    #pragma unroll
    for (int z = 0; z < 16; ++z) {
        ushort4 v = ((const ushort4*)(part + (size_t)z * 524288))[i];
        s.x += b2f(v.x); s.y += b2f(v.y); s.z += b2f(v.z); s.w += b2f(v.w);
    }
    ushort4 o;
    o.x = f2b(s.x); o.y = f2b(s.y); o.z = f2b(s.z); o.w = f2b(s.w);
    ((ushort4*)ght)[i] = o;
}

// ---------------- final: out = U * rsqrt(max(sqrt(nrm), eps)) ----------------
__global__ void final_norm(const unsigned short* __restrict__ U16, const float* __restrict__ nrm,
                           float* __restrict__ out) {
    int i = blockIdx.x * 256 + threadIdx.x;
    ushort4 u = ((const ushort4*)U16)[i];
    int row = i >> 7;
    float inv = 1.0f / fmaxf(sqrtf(nrm[row]), 1e-12f);
    float4 o;
    o.x = b2f(u.x) * inv; o.y = b2f(u.y) * inv; o.z = b2f(u.z) * inv; o.w = b2f(u.w) * inv;
    ((float4*)out)[i] = o;
}

extern "C" void kernel_launch(void* const* d_in, const int* in_sizes, int n_in,
                              void* d_out, int out_size, void* d_ws, size_t ws_size,
                              hipStream_t stream) {
    const float* x  = (const float*)d_in[0];
    const float* Wq = (const float*)d_in[1];
    const float* bq = (const float*)d_in[2];
    const float* Wk = (const float*)d_in[3];
    const float* bk = (const float*)d_in[4];
    const float* Wv = (const float*)d_in[5];
    const float* bv = (const float*)d_in[6];
    float* out = (float*)d_out;

    char* ws = (char*)d_ws;
    size_t off = 0;
    auto alloc = [&](size_t bytes) -> void* {
        void* p = ws + off;
        off = (off + bytes + 255) & ~(size_t)255;
        return p;
    };

    unsigned short* xb   = (unsigned short*)alloc((size_t)NTOK * DIM * 2);
    unsigned short* Wb   = (unsigned short*)alloc((size_t)QKVW * DIM * 2);
    float*          bc   = (float*)alloc(QKVW * 4);
    unsigned short* Qb   = (unsigned short*)alloc((size_t)NTOK * DIM * 2);
    unsigned short* KVt  = (unsigned short*)alloc((size_t)1024 * NTOK * 2);
    unsigned short* GHp  = (unsigned short*)alloc((size_t)16 * 1024 * 512 * 2);
    unsigned short* GHt  = (unsigned short*)alloc((size_t)1024 * 512 * 2);
    unsigned short* U16  = (unsigned short*)alloc((size_t)NTOK * DIM * 2);
    float*          nrm  = (float*)alloc(NTOK * 4);

    // fused prep: x->bf16 (4096 blk), W->bf16 (768), bias (6), nrm zero (8)
    prep<<<4878, 256, 0, stream>>>(x, Wq, Wk, Wv, bq, bk, bv, xb, Wb, bc, nrm);

    // QKV: Q -> Qb row-major; K/V -> KVt transposed. 128^2 tile, BK=64, NT=8
    gemm_qkv3<12, 8><<<dim3(QKVW / 128, NTOK / 128), 256, 0, stream>>>(
        xb, DIM, Wb, DIM, Qb, KVt, bc);

    // GHt partials (bf16): GHt = KVt @ Kt^T   [1024 x 512], K=8192 split 16, NT=8
    gemm8b<2, 0, 8><<<dim3(512 / 128, 1024 / 128, 16), 256, 0, stream>>>(
        KVt, NTOK, KVt, NTOK, GHp, 512, nullptr, nullptr);

    // GHt(bf16) = sum_z GHp[z]   [1024 x 512]
    reduce_gh<<<512, 256, 0, stream>>>(GHp, GHt);

    // TU = Q @ GHt^T: T-cols (bn<4) fused into nrm rowdot; U stored bf16. NT=8
    gemm8b<4, 8, 8><<<dim3(1024 / 128, NTOK / 128), 256, 0, stream>>>(
        Qb, 512, GHt, 512, U16, DIM, Qb, nrm);

    // out = U * rsqrt(max(sqrt(nrm), eps))
    final_norm<<<NTOK * DIM / 4 / 256, 256, 0, stream>>>(U16, nrm, out);
}